// Round 3
// baseline (943.831 us; speedup 1.0000x reference)
//
#include <hip/hip_runtime.h>
#include <hip/hip_bf16.h>

// FrozenBNBEmbedding: dequantize-blockwise (int8 codes -> fp32 via 256-entry LUT,
// per-4096-block absmax scale) fused with embedding gather.
// DIM == BLOCK == 4096  =>  one absmax scale per vocab row.
//
// R2: 4 rows/block (tokens+scales loaded up-front once per block — one
// dependent-chain stall per block, not per row), row-pairs processed with all
// 8 int4 loads in flight, plain float4 stores (nt was neutral-to-worse in R1).

#define DIM 4096
#define ROWS 4

typedef float f32x4 __attribute__((ext_vector_type(4)));

__global__ __launch_bounds__(256) void bnb_embed_kernel(
    const int* __restrict__ tokens,    // [n_tokens] token ids
    const int* __restrict__ weight,    // [VOCAB, DIM] int8 codes stored as int32
    const float* __restrict__ absmax,  // [VOCAB] per-row scale (n_blocks == VOCAB)
    const float* __restrict__ code,    // [256] LUT
    float* __restrict__ out,           // [n_tokens, DIM] fp32
    int n_tokens)
{
    __shared__ float lut[256];
    lut[threadIdx.x] = code[threadIdx.x];

    const int base = blockIdx.x * ROWS;

    // Issue all per-block uniform loads before the barrier: tokens first
    // (independent), then scales (dependent on tokens only).
    int t[ROWS];
#pragma unroll
    for (int r = 0; r < ROWS; ++r) {
        const int row = base + r;
        t[r] = (row < n_tokens) ? tokens[row] : 0;
    }
    float s[ROWS];
#pragma unroll
    for (int r = 0; r < ROWS; ++r) s[r] = absmax[t[r]];

    __syncthreads();

#pragma unroll
    for (int r = 0; r < ROWS; r += 2) {
        const int row0 = base + r;
        if (row0 >= n_tokens) break;
        const bool has1 = (row0 + 1) < n_tokens;

        const int4* __restrict__ w0 = (const int4*)(weight + (size_t)t[r] * DIM);
        const int4* __restrict__ w1 = (const int4*)(weight + (size_t)t[r + 1] * DIM);
        f32x4* __restrict__ o0 = (f32x4*)(out + (size_t)row0 * DIM);
        f32x4* __restrict__ o1 = o0 + DIM / 4;

        // All 8 independent 16B loads in flight before any dependent LDS use.
        int4 q0[4], q1[4];
#pragma unroll
        for (int i = 0; i < 4; ++i) q0[i] = w0[threadIdx.x + i * 256];
        if (has1) {
#pragma unroll
            for (int i = 0; i < 4; ++i) q1[i] = w1[threadIdx.x + i * 256];
        }

#pragma unroll
        for (int i = 0; i < 4; ++i) {
            const int idx = threadIdx.x + i * 256;
            f32x4 o;
            o.x = lut[q0[i].x & 255] * s[r];
            o.y = lut[q0[i].y & 255] * s[r];
            o.z = lut[q0[i].z & 255] * s[r];
            o.w = lut[q0[i].w & 255] * s[r];
            o0[idx] = o;
        }
        if (has1) {
#pragma unroll
            for (int i = 0; i < 4; ++i) {
                const int idx = threadIdx.x + i * 256;
                f32x4 o;
                o.x = lut[q1[i].x & 255] * s[r + 1];
                o.y = lut[q1[i].y & 255] * s[r + 1];
                o.z = lut[q1[i].z & 255] * s[r + 1];
                o.w = lut[q1[i].w & 255] * s[r + 1];
                o1[idx] = o;
            }
        }
    }
}

extern "C" void kernel_launch(void* const* d_in, const int* in_sizes, int n_in,
                              void* d_out, int out_size, void* d_ws, size_t ws_size,
                              hipStream_t stream)
{
    const int*   tokens = (const int*)d_in[0];    // [4, 2048] int32
    const int*   weight = (const int*)d_in[1];    // [50400, 4096] int32
    const float* absmax = (const float*)d_in[2];  // [50400] fp32
    const float* code   = (const float*)d_in[3];  // [256] fp32
    float*       out    = (float*)d_out;          // [4, 2048, 4096] fp32

    const int n_tokens = in_sizes[0];             // 8192
    const int grid = (n_tokens + ROWS - 1) / ROWS;
    bnb_embed_kernel<<<grid, 256, 0, stream>>>(tokens, weight, absmax, code, out, n_tokens);
}